// Round 3
// baseline (940.121 us; speedup 1.0000x reference)
//
#include <hip/hip_runtime.h>

#define CRF_B 256
#define CRF_S 1024
#define CRF_T 128
#define GSPLIT 8                    // gold: S-slices per batch (128 rows each)
#define WS_FWD  (CRF_B * GSPLIT)    // ws layout: [0,2048) gold partials,
#define WS_N    (WS_FWD + CRF_B)    //            [2048,2304) fwd results

typedef __attribute__((ext_vector_type(4))) float f32x4;

// Barrier that waits only on LDS ops (lgkmcnt), NOT vmcnt: keeps global
// em-prefetch loads in flight across steps (__syncthreads drains vmcnt(0)).
__device__ __forceinline__ void barrier_lds_only() {
    __asm__ volatile("s_waitcnt lgkmcnt(0)\n\ts_barrier" ::: "memory");
}

// Cross-lane butterfly adds on the VALU pipe (DPP), no LDS/bpermute.
__device__ __forceinline__ float dpp_add_xor1(float x) {      // quad_perm [1,0,3,2]
    int y = __builtin_amdgcn_mov_dpp(__float_as_int(x), 0xB1, 0xF, 0xF, false);
    return x + __int_as_float(y);
}
__device__ __forceinline__ float dpp_add_xor2(float x) {      // quad_perm [2,3,0,1]
    int y = __builtin_amdgcn_mov_dpp(__float_as_int(x), 0x4E, 0xF, 0xF, false);
    return x + __int_as_float(y);
}
// After xor1+xor2 the value is quad-uniform, so ROW_HALF_MIRROR (lane^7 within
// 8) acts as xor4: combines the two quads of each 8-lane row group.
__device__ __forceinline__ float dpp_add_xor4u(float x) {     // ROW_HALF_MIRROR
    int y = __builtin_amdgcn_mov_dpp(__float_as_int(x), 0x141, 0xF, 0xF, false);
    return x + __int_as_float(y);
}

__device__ __forceinline__ f32x4 exp4(f32x4 v) {
    f32x4 r;
    r.x = __expf(v.x); r.y = __expf(v.y); r.z = __expf(v.z); r.w = __expf(v.w);
    return r;
}
__device__ __forceinline__ float hsum4(f32x4 v) {
    return (v.x + v.y) + (v.z + v.w);
}

// ---------------------------------------------------------------------------
// Kernel 1: tag-gather terms (negated) + S2 (unchanged from R2: GSPLIT blocks,
// partials to ws, no atomics).
// ---------------------------------------------------------------------------
__global__ __launch_bounds__(256) void crf_gold_kernel(
    const float* __restrict__ em, const int* __restrict__ tags,
    const float* __restrict__ mask, const float* __restrict__ startT,
    const float* __restrict__ endT, const float* __restrict__ trans,
    float* __restrict__ ws)
{
    const int b     = blockIdx.x >> 3;            // GSPLIT == 8
    const int slice = blockIdx.x & (GSPLIT - 1);
    const int base  = slice << 7;                 // 128 rows per slice
    const int tid = threadIdx.x;
    const int p = tid & 3;      // quad member
    const int q = tid >> 2;     // quad id 0..63
    const int* tg = tags + (size_t)b * CRF_S;
    const float* mk = mask + (size_t)b * CRF_S;
    const float* emr = em + (size_t)b * CRF_S * CRF_T;

    float g_acc = 0.f;
    if (tid < 128) {
        const int t = base + tid;
        const int tagt = tg[t];
        const float m = mk[t];
        g_acc += emr[(size_t)t * CRF_T + tagt] * m;
        if (t >= 1) g_acc += trans[tg[t - 1] * CRF_T + tagt] * m;
    }
    if (tid == 0 && slice == 0)
        g_acc += startT[tg[0]];
    if (tid == 0 && slice == GSPLIT - 1)
        g_acc += endT[tg[CRF_S - 1]] * mk[CRF_S - 1];

    float s2 = 0.f;
#pragma unroll
    for (int it = 0; it < 2; ++it) {
        const int r = base + it * 64 + q;
        const float* row = emr + (size_t)r * CRF_T;
        f32x4 sum4 = {0.f, 0.f, 0.f, 0.f};
#pragma unroll
        for (int k = 0; k < 8; ++k)
            sum4 += exp4(*(const f32x4*)(row + k * 16 + p * 4));
        float s = hsum4(sum4);
        s = dpp_add_xor1(s);
        s = dpp_add_xor2(s);
        if (p == 0) s2 += __logf(s) * mk[r];
    }

    float contrib = s2 - g_acc;
#pragma unroll
    for (int d = 1; d < 64; d <<= 1) contrib += __shfl_xor(contrib, d);
    __shared__ float r4[4];
    if ((tid & 63) == 0) r4[tid >> 6] = contrib;
    __syncthreads();
    if (tid == 0)
        ws[blockIdx.x] = (r4[0] + r4[1]) + (r4[2] + r4[3]);
}

// ---------------------------------------------------------------------------
// Kernel 2: forward recursion, TWO CHAINS PER BLOCK fused by ILP (not TLP).
// R0's proven 4-wave structure per chain (r=tid&7 row group, cq=tid>>3 col
// quad, E 16x4 tile in regs, swizzled ds_read_b128, DPP reduce). The two
// chains share the SAME EE registers (same transitions). Per ROUND:
//   issue both chains' ds_reads -> chain0 FMA/reduce/write ->
//   chain1 FMA/reduce/write -> ONE lgkm-only barrier.
// Chain1's independent FMAs fill chain0's read-latency + DPP-tree stalls
// (R1's failure was separate waves locked to one barrier; here the overlap
// is in-stream ILP, immune to wave scheduling). Barriers per chain-step: 0.5.
// ---------------------------------------------------------------------------
__global__ __launch_bounds__(256, 1) void crf_fwd_kernel(
    const float* __restrict__ em, const float* __restrict__ mask,
    const float* __restrict__ startT, const float* __restrict__ endT,
    const float* __restrict__ trans, float* __restrict__ ws)
{
    const int tid = threadIdx.x;
    const int b0 = blockIdx.x * 2, b1 = b0 + 1;
    const int r = tid & 7;       // row group: rows r*16 .. r*16+15
    const int cq = tid >> 3;     // 0..31
    const int j0 = cq * 4;
    const bool leader = (r == 0);

    __shared__ __align__(16) float Abuf[2][2][CRF_T];   // [chain][buf][col]
    __shared__ __align__(16) float partsA[2][32];
    __shared__ float red[8];
    __shared__ float lzsh[2];

    // k-swizzle: thread's 4 b128 reads at float-idx r*16 + ((k+r)&3)*4.
    int kidx[4];
#pragma unroll
    for (int k = 0; k < 4; ++k) kidx[k] = (k + r) & 3;

    // EE[k][c][s] = exp(trans[i][j0+c]), i = r*16 + kidx[k]*4 + s  (64 VGPRs,
    // shared by both chains).
    f32x4 EE[4][4];
#pragma unroll
    for (int k = 0; k < 4; ++k) {
#pragma unroll
        for (int s = 0; s < 4; ++s) {
            const int i = r * 16 + kidx[k] * 4 + s;
            f32x4 t4 = *(const f32x4*)&trans[i * CRF_T + j0];
            EE[k][0][s] = __expf(t4.x);
            EE[k][1][s] = __expf(t4.y);
            EE[k][2][s] = __expf(t4.z);
            EE[k][3][s] = __expf(t4.w);
        }
    }

    const float* emb0 = em + (size_t)b0 * CRF_S * CRF_T + j0;
    const float* emb1 = em + (size_t)b1 * CRF_S * CRF_T + j0;
    const float ml0 = mask[(size_t)b0 * CRF_S + (CRF_S - 1)];
    const float ml1 = mask[(size_t)b1 * CRF_S + (CRF_S - 1)];

    float logZ0 = 0.f, rc0 = 1.f;   // leaders only
    float logZ1 = 0.f, rc1 = 1.f;

    // em pipeline per chain: eh[cur] in use, eh[nxt] built this group;
    // emv = group g+2 (distance-2 prefetch, ~8 rounds ahead >> HBM latency).
    f32x4 emv0[4], emv1[4], eh0[2][4], eh1[2][4];
#pragma unroll
    for (int k = 0; k < 4; ++k) emv0[k] = *(const f32x4*)(emb0 + (size_t)k * CRF_T);
#pragma unroll
    for (int k = 0; k < 4; ++k) emv1[k] = *(const f32x4*)(emb1 + (size_t)k * CRF_T);
#pragma unroll
    for (int k = 0; k < 4; ++k) eh0[0][k] = exp4(emv0[k]);
#pragma unroll
    for (int k = 0; k < 4; ++k) eh1[0][k] = exp4(emv1[k]);
#pragma unroll
    for (int k = 0; k < 4; ++k) emv0[k] = *(const f32x4*)(emb0 + (size_t)(4 + k) * CRF_T);
#pragma unroll
    for (int k = 0; k < 4; ++k) emv1[k] = *(const f32x4*)(emb1 + (size_t)(4 + k) * CRF_T);

    auto ROUND = [&](int t, int role, f32x4 e0, f32x4 e1) {
        const int rb = (t & 1) ^ 1, wb = t & 1;

        // ---- issue both chains' alpha reads up front ----
        const f32x4* A0 = (const f32x4*)&Abuf[0][rb][r * 16];
        const f32x4* A1 = (const f32x4*)&Abuf[1][rb][r * 16];
        f32x4 av0[4], av1[4];
#pragma unroll
        for (int k = 0; k < 4; ++k) av0[k] = A0[kidx[k]];
#pragma unroll
        for (int k = 0; k < 4; ++k) av1[k] = A1[kidx[k]];

        // t==1023's rescale is never applied -> must NOT enter logZ.
        if (role == 3 && leader && t < 1023) {
            const f32x4* p0 = (const f32x4*)partsA[0];
            const f32x4* p1 = (const f32x4*)partsA[1];
            f32x4 s80 = ((p0[0] + p0[1]) + (p0[2] + p0[3])) +
                        ((p0[4] + p0[5]) + (p0[6] + p0[7]));
            f32x4 s81 = ((p1[0] + p1[1]) + (p1[2] + p1[3])) +
                        ((p1[4] + p1[5]) + (p1[6] + p1[7]));
            float c0 = hsum4(s80), c1 = hsum4(s81);
            rc0 = __builtin_amdgcn_rcpf(c0); logZ0 += __logf(c0);
            rc1 = __builtin_amdgcn_rcpf(c1); logZ1 += __logf(c1);
        }

        // ---- chain 0 compute ----
        {
            f32x4 ac0 = {0.f, 0.f, 0.f, 0.f}, ac1 = ac0, ac2 = ac0, ac3 = ac0;
#pragma unroll
            for (int k = 0; k < 4; ++k) {
                f32x4 av = av0[k];
                ac0 = __builtin_elementwise_fma(av, EE[k][0], ac0);
                ac1 = __builtin_elementwise_fma(av, EE[k][1], ac1);
                ac2 = __builtin_elementwise_fma(av, EE[k][2], ac2);
                ac3 = __builtin_elementwise_fma(av, EE[k][3], ac3);
            }
            float d0 = hsum4(ac0), d1 = hsum4(ac1), d2 = hsum4(ac2), d3 = hsum4(ac3);
            d0 = dpp_add_xor4u(dpp_add_xor2(dpp_add_xor1(d0)));
            d1 = dpp_add_xor4u(dpp_add_xor2(dpp_add_xor1(d1)));
            d2 = dpp_add_xor4u(dpp_add_xor2(dpp_add_xor1(d2)));
            d3 = dpp_add_xor4u(dpp_add_xor2(dpp_add_xor1(d3)));
            float a0 = d0 * e0.x, a1 = d1 * e0.y, a2 = d2 * e0.z, a3 = d3 * e0.w;
            if (role == 0) { a0 *= rc0; a1 *= rc0; a2 *= rc0; a3 *= rc0; }
            if (leader) {
                f32x4 av = {a0, a1, a2, a3};
                *(f32x4*)&Abuf[0][wb][j0] = av;
                if (role == 2) partsA[0][cq] = (a0 + a1) + (a2 + a3);
            }
        }
        // ---- chain 1 compute ----
        {
            f32x4 ac0 = {0.f, 0.f, 0.f, 0.f}, ac1 = ac0, ac2 = ac0, ac3 = ac0;
#pragma unroll
            for (int k = 0; k < 4; ++k) {
                f32x4 av = av1[k];
                ac0 = __builtin_elementwise_fma(av, EE[k][0], ac0);
                ac1 = __builtin_elementwise_fma(av, EE[k][1], ac1);
                ac2 = __builtin_elementwise_fma(av, EE[k][2], ac2);
                ac3 = __builtin_elementwise_fma(av, EE[k][3], ac3);
            }
            float d0 = hsum4(ac0), d1 = hsum4(ac1), d2 = hsum4(ac2), d3 = hsum4(ac3);
            d0 = dpp_add_xor4u(dpp_add_xor2(dpp_add_xor1(d0)));
            d1 = dpp_add_xor4u(dpp_add_xor2(dpp_add_xor1(d1)));
            d2 = dpp_add_xor4u(dpp_add_xor2(dpp_add_xor1(d2)));
            d3 = dpp_add_xor4u(dpp_add_xor2(dpp_add_xor1(d3)));
            float a0 = d0 * e1.x, a1 = d1 * e1.y, a2 = d2 * e1.z, a3 = d3 * e1.w;
            if (role == 0) { a0 *= rc1; a1 *= rc1; a2 *= rc1; a3 *= rc1; }
            if (leader) {
                f32x4 av = {a0, a1, a2, a3};
                *(f32x4*)&Abuf[1][wb][j0] = av;
                if (role == 2) partsA[1][cq] = (a0 + a1) + (a2 + a3);
            }
        }
        barrier_lds_only();
    };

    // ---- group 0: t=0 init + rounds 1..3 ----
    {
        f32x4 s4 = *(const f32x4*)&startT[j0];
        f32x4 es;
        es.x = __expf(s4.x); es.y = __expf(s4.y);
        es.z = __expf(s4.z); es.w = __expf(s4.w);
        if (leader) {
            f32x4 a0 = es * eh0[0][0];
            f32x4 a1 = es * eh1[0][0];
            *(f32x4*)&Abuf[0][0][j0] = a0;
            *(f32x4*)&Abuf[1][0][j0] = a1;
        }
        barrier_lds_only();
        ROUND(1, 1, eh0[0][1], eh1[0][1]);
#pragma unroll
        for (int k = 0; k < 4; ++k) { eh0[1][k] = exp4(emv0[k]); eh1[1][k] = exp4(emv1[k]); }
        ROUND(2, 2, eh0[0][2], eh1[0][2]);
#pragma unroll
        for (int k = 0; k < 4; ++k) {
            emv0[k] = *(const f32x4*)(emb0 + (size_t)(8 + k) * CRF_T);
            emv1[k] = *(const f32x4*)(emb1 + (size_t)(8 + k) * CRF_T);
        }
        ROUND(3, 3, eh0[0][3], eh1[0][3]);
    }

    // ---- groups 1..255 ----
#pragma unroll 1
    for (int g = 1; g < 256; ++g) {
        const int t0 = 4 * g;
        const int cur = g & 1, nxt = cur ^ 1;
        ROUND(t0 + 0, 0, eh0[cur][0], eh1[cur][0]);
        ROUND(t0 + 1, 1, eh0[cur][1], eh1[cur][1]);
        if (g <= 254) {
#pragma unroll
            for (int k = 0; k < 4; ++k) { eh0[nxt][k] = exp4(emv0[k]); eh1[nxt][k] = exp4(emv1[k]); }
        }
        ROUND(t0 + 2, 2, eh0[cur][2], eh1[cur][2]);
        if (g <= 253) {
#pragma unroll
            for (int k = 0; k < 4; ++k) {
                emv0[k] = *(const f32x4*)(emb0 + (size_t)(t0 + 8 + k) * CRF_T);
                emv1[k] = *(const f32x4*)(emb1 + (size_t)(t0 + 8 + k) * CRF_T);
            }
        }
        ROUND(t0 + 3, 3, eh0[cur][3], eh1[cur][3]);
    }

    // ---- finale: A~_1023 in Abuf[c][1]; logZ in leader lanes ----
    __syncthreads();
    if (tid == 0) { lzsh[0] = logZ0; lzsh[1] = logZ1; }
    __syncthreads();

    // half h = tid>>7 handles chain h; jj = tid&127 its column.
    const int h = tid >> 7;
    const int jj = tid & 127;
    const float lz = lzsh[h];
    const float ml = h ? ml1 : ml0;
    float v = (__logf(Abuf[h][1][jj]) + lz) * ml + endT[jj];
    float mx = v;
#pragma unroll
    for (int dd = 1; dd < 64; dd <<= 1) mx = fmaxf(mx, __shfl_xor(mx, dd));
    if ((tid & 63) == 0) red[tid >> 6] = mx;
    __syncthreads();
    mx = fmaxf(red[h * 2], red[h * 2 + 1]);
    float ex = __expf(v - mx);
#pragma unroll
    for (int dd = 1; dd < 64; dd <<= 1) ex += __shfl_xor(ex, dd);
    if ((tid & 63) == 0) red[4 + (tid >> 6)] = ex;
    __syncthreads();
    if (jj == 0)
        ws[WS_FWD + b0 + h] = mx + __logf(red[4 + h * 2] + red[4 + h * 2 + 1]);
}

// ---------------------------------------------------------------------------
// Kernel 3: sum the 2304 ws partials, scale by 1/B (unchanged from R2).
// ---------------------------------------------------------------------------
__global__ __launch_bounds__(256) void crf_reduce_kernel(
    const float* __restrict__ ws, float* __restrict__ out)
{
    const int tid = threadIdx.x;
    float s = 0.f;
#pragma unroll
    for (int k = 0; k < WS_N; k += 256) s += ws[k + tid];   // WS_N = 9*256
#pragma unroll
    for (int d = 1; d < 64; d <<= 1) s += __shfl_xor(s, d);
    __shared__ float r4[4];
    if ((tid & 63) == 0) r4[tid >> 6] = s;
    __syncthreads();
    if (tid == 0)
        out[0] = ((r4[0] + r4[1]) + (r4[2] + r4[3])) * (1.0f / CRF_B);
}

// ---------------------------------------------------------------------------
extern "C" void kernel_launch(void* const* d_in, const int* in_sizes, int n_in,
                              void* d_out, int out_size, void* d_ws, size_t ws_size,
                              hipStream_t stream)
{
    const float* em     = (const float*)d_in[0];
    const int*   tags   = (const int*)d_in[1];
    const float* mask   = (const float*)d_in[2];
    const float* startT = (const float*)d_in[3];
    const float* endT   = (const float*)d_in[4];
    const float* trans  = (const float*)d_in[5];
    float* out = (float*)d_out;
    float* ws  = (float*)d_ws;

    hipLaunchKernelGGL(crf_gold_kernel, dim3(CRF_B * GSPLIT), dim3(256), 0, stream,
                       em, tags, mask, startT, endT, trans, ws);
    hipLaunchKernelGGL(crf_fwd_kernel, dim3(CRF_B / 2), dim3(256), 0, stream,
                       em, mask, startT, endT, trans, ws);
    hipLaunchKernelGGL(crf_reduce_kernel, dim3(1), dim3(256), 0, stream,
                       ws, out);
}

// Round 4
// 597.091 us; speedup vs baseline: 1.5745x; 1.5745x over previous
//
#include <hip/hip_runtime.h>

#define CRF_B 256
#define CRF_S 1024
#define CRF_T 128
#define GSPLIT 8                     // gold: S-slices per batch (128 rows each)
#define NFWD   CRF_B                 // fused grid: blocks [0,256) = fwd chains
#define NGOLD  (CRF_B * GSPLIT)      //             blocks [256, 2304) = gold
#define WS_FWD (CRF_B * GSPLIT)      // ws: [0,2048) gold partials,
#define WS_N   (WS_FWD + CRF_B)      //     [2048,2304) fwd results

typedef __attribute__((ext_vector_type(4))) float f32x4;

// Barrier that waits only on LDS ops (lgkmcnt), NOT vmcnt: keeps global
// em-prefetch loads in flight across steps.
__device__ __forceinline__ void barrier_lds_only() {
    __asm__ volatile("s_waitcnt lgkmcnt(0)\n\ts_barrier" ::: "memory");
}

// Cross-lane butterfly adds on the VALU pipe (DPP quad_perm).
__device__ __forceinline__ float dpp_add_xor1(float x) {      // [1,0,3,2]
    int y = __builtin_amdgcn_mov_dpp(__float_as_int(x), 0xB1, 0xF, 0xF, false);
    return x + __int_as_float(y);
}
__device__ __forceinline__ float dpp_add_xor2(float x) {      // [2,3,0,1]
    int y = __builtin_amdgcn_mov_dpp(__float_as_int(x), 0x4E, 0xF, 0xF, false);
    return x + __int_as_float(y);
}

__device__ __forceinline__ f32x4 exp4(f32x4 v) {
    f32x4 r;
    r.x = __expf(v.x); r.y = __expf(v.y); r.z = __expf(v.z); r.w = __expf(v.w);
    return r;
}
__device__ __forceinline__ float hsum4(f32x4 v) {
    return (v.x + v.y) + (v.z + v.w);
}

// ---------------------------------------------------------------------------
// FWD block body (128 threads = 2 waves). Lane: r = tid&3 owns rows
// [32r,32r+32) as 8 swizzled ds_read_b128; cq = tid>>2 owns cols 4cq..4cq+3.
// vs R0 (4 waves, r=tid&7):
//   - reduce group = one quad -> DPP tree 3 stages -> 2 (pure quad_perm)
//   - barrier syncs 2 waves, not 4
//   - swizzle kidx[k]=(k+2r)&7: slot k's four r-lanes hit 4 DISTINCT bank
//     quads (rows stride 128B = full bank wrap, so bank = 4m only; m =
//     k+2r mod 8 distinct across r) with 16-lane same-address broadcast
//     -> conflict-free (R0 paid 64 conflict-cyc/step).
// Total ds_read_b128 per step unchanged (16) -> LDS pipe cost same as R0;
// R2's mistake (66 LDS instr/step) not repeated.
// ---------------------------------------------------------------------------
__device__ __forceinline__ void fwd_block(
    const int b, const int tid,
    const float* __restrict__ em, const float* __restrict__ mask,
    const float* __restrict__ startT, const float* __restrict__ endT,
    const float* __restrict__ trans, float* __restrict__ ws)
{
    const int r  = tid & 3;           // row group: rows 32r .. 32r+31
    const int cq = tid >> 2;          // 0..31
    const int j0 = cq * 4;
    const bool leader = (r == 0);

    __shared__ __align__(16) float Abuf[2][CRF_T];
    __shared__ __align__(16) float partsA[32];
    __shared__ float red[4];
    __shared__ float lzsh;

    // read-slot swizzle (see header comment)
    int kidx[8];
#pragma unroll
    for (int k = 0; k < 8; ++k) kidx[k] = (k + 2 * r) & 7;

    // EE[k][c][s] = exp(trans[32r + 4*kidx[k] + s][j0+c])  (128 VGPRs)
    f32x4 EE[8][4];
#pragma unroll
    for (int k = 0; k < 8; ++k) {
#pragma unroll
        for (int s = 0; s < 4; ++s) {
            const int i = 32 * r + 4 * kidx[k] + s;
            f32x4 t4 = *(const f32x4*)&trans[i * CRF_T + j0];
            EE[k][0][s] = __expf(t4.x);
            EE[k][1][s] = __expf(t4.y);
            EE[k][2][s] = __expf(t4.z);
            EE[k][3][s] = __expf(t4.w);
        }
    }

    const float* emb = em + (size_t)b * CRF_S * CRF_T + j0;
    const float mlast = mask[(size_t)b * CRF_S + (CRF_S - 1)];

    float logZ = 0.f;   // leaders only
    float rc = 1.f;     // leaders only

    // em pipeline: eh[cur] in use, eh[nxt] built this group; emv = group g+2.
    f32x4 emv[4], eh[2][4];
#pragma unroll
    for (int k = 0; k < 4; ++k) emv[k] = *(const f32x4*)(emb + (size_t)k * CRF_T);
#pragma unroll
    for (int k = 0; k < 4; ++k) eh[0][k] = exp4(emv[k]);
#pragma unroll
    for (int k = 0; k < 4; ++k) emv[k] = *(const f32x4*)(emb + (size_t)(4 + k) * CRF_T);

    auto STEP = [&](int t, int role, f32x4 ehv) {
        const int rb = (t & 1) ^ 1, wb = t & 1;

        // t==1023's rescale is never applied -> must NOT enter logZ.
        if (role == 3 && leader && t < 1023) {
            const f32x4* pa = (const f32x4*)partsA;   // csum written at t-1
            f32x4 s8 = ((pa[0] + pa[1]) + (pa[2] + pa[3])) +
                       ((pa[4] + pa[5]) + (pa[6] + pa[7]));
            float c = hsum4(s8);
            rc = __builtin_amdgcn_rcpf(c);
            logZ += __logf(c);
        }

        const f32x4* A4 = (const f32x4*)&Abuf[rb][32 * r];
        f32x4 av = A4[kidx[0]];
        f32x4 ac0 = av * EE[0][0];
        f32x4 ac1 = av * EE[0][1];
        f32x4 ac2 = av * EE[0][2];
        f32x4 ac3 = av * EE[0][3];
#pragma unroll
        for (int k = 1; k < 8; ++k) {
            av = A4[kidx[k]];
            ac0 = __builtin_elementwise_fma(av, EE[k][0], ac0);
            ac1 = __builtin_elementwise_fma(av, EE[k][1], ac1);
            ac2 = __builtin_elementwise_fma(av, EE[k][2], ac2);
            ac3 = __builtin_elementwise_fma(av, EE[k][3], ac3);
        }
        float d0 = hsum4(ac0), d1 = hsum4(ac1), d2 = hsum4(ac2), d3 = hsum4(ac3);
        d0 = dpp_add_xor2(dpp_add_xor1(d0));
        d1 = dpp_add_xor2(dpp_add_xor1(d1));
        d2 = dpp_add_xor2(dpp_add_xor1(d2));
        d3 = dpp_add_xor2(dpp_add_xor1(d3));

        float a0 = d0 * ehv.x, a1 = d1 * ehv.y, a2 = d2 * ehv.z, a3 = d3 * ehv.w;
        if (role == 0) { a0 *= rc; a1 *= rc; a2 *= rc; a3 *= rc; }
        if (leader) {
            f32x4 avw = {a0, a1, a2, a3};
            *(f32x4*)&Abuf[wb][j0] = avw;
            if (role == 2) partsA[cq] = (a0 + a1) + (a2 + a3);
        }
        barrier_lds_only();
    };

    // ---- group 0: t=0 init + steps 1..3 ----
    {
        f32x4 s4 = *(const f32x4*)&startT[j0];
        if (leader) {
            f32x4 a;
            a.x = __expf(s4.x) * eh[0][0].x;
            a.y = __expf(s4.y) * eh[0][0].y;
            a.z = __expf(s4.z) * eh[0][0].z;
            a.w = __expf(s4.w) * eh[0][0].w;
            *(f32x4*)&Abuf[0][j0] = a;
        }
        barrier_lds_only();
        STEP(1, 1, eh[0][1]);
#pragma unroll
        for (int k = 0; k < 4; ++k) eh[1][k] = exp4(emv[k]);   // group 1
        STEP(2, 2, eh[0][2]);
#pragma unroll
        for (int k = 0; k < 4; ++k) emv[k] = *(const f32x4*)(emb + (size_t)(8 + k) * CRF_T); // group 2
        STEP(3, 3, eh[0][3]);
    }

    // ---- groups 1..255 ----
#pragma unroll 1
    for (int g = 1; g < 256; ++g) {
        const int t0 = 4 * g;
        const int cur = g & 1, nxt = cur ^ 1;
        STEP(t0 + 0, 0, eh[cur][0]);
        STEP(t0 + 1, 1, eh[cur][1]);
        if (g <= 254) {
#pragma unroll
            for (int k = 0; k < 4; ++k) eh[nxt][k] = exp4(emv[k]);  // group g+1
        }
        STEP(t0 + 2, 2, eh[cur][2]);
        if (g <= 253) {
#pragma unroll
            for (int k = 0; k < 4; ++k)
                emv[k] = *(const f32x4*)(emb + (size_t)(t0 + 8 + k) * CRF_T); // group g+2
        }
        STEP(t0 + 3, 3, eh[cur][3]);
    }

    // ---- finale: A~_1023 in Abuf[1]; logZ in leader lanes ----
    __syncthreads();
    if (tid == 0) lzsh = logZ;
    __syncthreads();
    const float lz = lzsh;

    float v = (__logf(Abuf[1][tid]) + lz) * mlast + endT[tid];
    float mx = v;
#pragma unroll
    for (int dd = 1; dd < 64; dd <<= 1) mx = fmaxf(mx, __shfl_xor(mx, dd));
    if ((tid & 63) == 0) red[tid >> 6] = mx;
    __syncthreads();
    mx = fmaxf(red[0], red[1]);
    float ex = __expf(v - mx);
#pragma unroll
    for (int dd = 1; dd < 64; dd <<= 1) ex += __shfl_xor(ex, dd);
    if ((tid & 63) == 0) red[2 + (tid >> 6)] = ex;
    __syncthreads();
    if (tid == 0)
        ws[WS_FWD + b] = mx + __logf(red[2] + red[3]);
}

// ---------------------------------------------------------------------------
// GOLD block body (128 threads): tag-gather (negated) + S2 for a 128-row
// slice. Partial to ws[gb]. Runs CONCURRENTLY with fwd blocks (same launch),
// filling the idle SIMD slots of the latency-bound fwd chains.
// ---------------------------------------------------------------------------
__device__ __forceinline__ void gold_block(
    const int gb, const int tid,
    const float* __restrict__ em, const int* __restrict__ tags,
    const float* __restrict__ mask, const float* __restrict__ startT,
    const float* __restrict__ endT, const float* __restrict__ trans,
    float* __restrict__ ws)
{
    const int b     = gb >> 3;                    // GSPLIT == 8
    const int slice = gb & (GSPLIT - 1);
    const int base  = slice << 7;                 // 128 rows per slice
    const int p = tid & 3;      // quad member
    const int q = tid >> 2;     // quad id 0..31
    const int* tg = tags + (size_t)b * CRF_S;
    const float* mk = mask + (size_t)b * CRF_S;
    const float* emr = em + (size_t)b * CRF_S * CRF_T;

    __shared__ float r2g[2];

    // ---- tag-gather: one t per thread ----
    float g_acc = 0.f;
    {
        const int t = base + tid;
        const int tagt = tg[t];
        const float m = mk[t];
        g_acc += emr[(size_t)t * CRF_T + tagt] * m;
        if (t >= 1) g_acc += trans[tg[t - 1] * CRF_T + tagt] * m;
    }
    if (tid == 0 && slice == 0)
        g_acc += startT[tg[0]];
    if (tid == 0 && slice == GSPLIT - 1)
        g_acc += endT[tg[CRF_S - 1]] * mk[CRF_S - 1];

    // ---- S2: quad q handles rows base+q+32*it; lane p cols 4p+16k ----
    float s2 = 0.f;
#pragma unroll
    for (int it = 0; it < 4; ++it) {
        const int rr = base + it * 32 + q;
        const float* row = emr + (size_t)rr * CRF_T;
        f32x4 sum4 = {0.f, 0.f, 0.f, 0.f};
#pragma unroll
        for (int k = 0; k < 8; ++k)
            sum4 += exp4(*(const f32x4*)(row + k * 16 + p * 4));
        float s = hsum4(sum4);
        s = dpp_add_xor1(s);
        s = dpp_add_xor2(s);
        if (p == 0) s2 += __logf(s) * mk[rr];
    }

    float contrib = s2 - g_acc;
#pragma unroll
    for (int d = 1; d < 64; d <<= 1) contrib += __shfl_xor(contrib, d);
    if ((tid & 63) == 0) r2g[tid >> 6] = contrib;
    __syncthreads();
    if (tid == 0)
        ws[gb] = r2g[0] + r2g[1];
}

// ---------------------------------------------------------------------------
// Fused kernel: blocks [0,NFWD) = fwd chains (dispatched first, ~1 per CU);
// blocks [NFWD, NFWD+NGOLD) = gold slices filling the remaining capacity.
// ---------------------------------------------------------------------------
__global__ __launch_bounds__(128, 1) void crf_main_kernel(
    const float* __restrict__ em, const int* __restrict__ tags,
    const float* __restrict__ mask, const float* __restrict__ startT,
    const float* __restrict__ endT, const float* __restrict__ trans,
    float* __restrict__ ws)
{
    if (blockIdx.x < NFWD)
        fwd_block(blockIdx.x, threadIdx.x, em, mask, startT, endT, trans, ws);
    else
        gold_block(blockIdx.x - NFWD, threadIdx.x, em, tags, mask, startT,
                   endT, trans, ws);
}

// ---------------------------------------------------------------------------
// Reduce: sum the 2304 ws partials (2048 gold, negated + 256 fwd), /B.
// ---------------------------------------------------------------------------
__global__ __launch_bounds__(256) void crf_reduce_kernel(
    const float* __restrict__ ws, float* __restrict__ out)
{
    const int tid = threadIdx.x;
    float s = 0.f;
#pragma unroll
    for (int k = 0; k < WS_N; k += 256) s += ws[k + tid];   // WS_N = 9*256
#pragma unroll
    for (int d = 1; d < 64; d <<= 1) s += __shfl_xor(s, d);
    __shared__ float r4[4];
    if ((tid & 63) == 0) r4[tid >> 6] = s;
    __syncthreads();
    if (tid == 0)
        out[0] = ((r4[0] + r4[1]) + (r4[2] + r4[3])) * (1.0f / CRF_B);
}

// ---------------------------------------------------------------------------
extern "C" void kernel_launch(void* const* d_in, const int* in_sizes, int n_in,
                              void* d_out, int out_size, void* d_ws, size_t ws_size,
                              hipStream_t stream)
{
    const float* em     = (const float*)d_in[0];
    const int*   tags   = (const int*)d_in[1];
    const float* mask   = (const float*)d_in[2];
    const float* startT = (const float*)d_in[3];
    const float* endT   = (const float*)d_in[4];
    const float* trans  = (const float*)d_in[5];
    float* out = (float*)d_out;
    float* ws  = (float*)d_ws;

    hipLaunchKernelGGL(crf_main_kernel, dim3(NFWD + NGOLD), dim3(128), 0, stream,
                       em, tags, mask, startT, endT, trans, ws);
    hipLaunchKernelGGL(crf_reduce_kernel, dim3(1), dim3(256), 0, stream,
                       ws, out);
}